// Round 3
// baseline (3010.266 us; speedup 1.0000x reference)
//
#include <hip/hip_runtime.h>
#include <math.h>

#define SEQLEN 1024
#define DIM 512
#define MM 512

typedef float f32x4 __attribute__((ext_vector_type(4)));

__device__ __forceinline__ float sigf(float x) {
  return __builtin_amdgcn_rcpf(1.0f + __expf(-x));
}
__device__ __forceinline__ float tanhfast(float x) {
  return 1.0f - 2.0f * __builtin_amdgcn_rcpf(1.0f + __expf(2.0f * x));
}

// ---------------- K1: Gx[seq][t][g] = emb[ids[t]] . Wxcat[g] + bias_cat[g] ----------------
// Wxcat rows: [Wioux (1536 rows); Wfx (512 rows)], 512 cols.  Gx: [2][1024][2048]
__global__ __launch_bounds__(256) void gx_gemm(
    const int* __restrict__ l_ids, const int* __restrict__ r_ids,
    const float* __restrict__ emb,
    const float* __restrict__ Wioux, const float* __restrict__ Wfx,
    const float* __restrict__ bioux, const float* __restrict__ biouh,
    const float* __restrict__ bfx, const float* __restrict__ bfh,
    float* __restrict__ gx)
{
  __shared__ __align__(16) float At[32][68];   // transposed tiles: [k][row]
  __shared__ __align__(16) float Bt[32][68];
  const int tid = threadIdx.x;
  const int bid = blockIdx.x;
  const int seq = bid >> 9;            // 2
  const int tt  = (bid >> 5) & 15;     // 16 t-tiles of 64
  const int gt  = bid & 31;            // 32 g-tiles of 64
  const int t0 = tt * 64, g0 = gt * 64;
  const int* ids = seq ? r_ids : l_ids;

  const int li = tid >> 2;             // 0..63 (tile row)
  const int lk = (tid & 3) * 8;        // k chunk
  const float* arow = emb + (size_t)ids[t0 + li] * DIM;
  const int gg = g0 + li;
  const float* brow = (gg < 1536) ? (Wioux + (size_t)gg * DIM)
                                  : (Wfx + (size_t)(gg - 1536) * DIM);
  const int tr = tid >> 4;             // 0..15 micro-row group
  const int tc = tid & 15;             // 0..15 micro-col group

  float acc[4][4];
  #pragma unroll
  for (int i = 0; i < 4; ++i) { acc[i][0]=0.f; acc[i][1]=0.f; acc[i][2]=0.f; acc[i][3]=0.f; }

  for (int kb = 0; kb < 16; ++kb) {
    const int k0 = kb * 32;
    float4 av0 = *(const float4*)(arow + k0 + lk);
    float4 av1 = *(const float4*)(arow + k0 + lk + 4);
    float4 bv0 = *(const float4*)(brow + k0 + lk);
    float4 bv1 = *(const float4*)(brow + k0 + lk + 4);
    __syncthreads();
    At[lk+0][li]=av0.x; At[lk+1][li]=av0.y; At[lk+2][li]=av0.z; At[lk+3][li]=av0.w;
    At[lk+4][li]=av1.x; At[lk+5][li]=av1.y; At[lk+6][li]=av1.z; At[lk+7][li]=av1.w;
    Bt[lk+0][li]=bv0.x; Bt[lk+1][li]=bv0.y; Bt[lk+2][li]=bv0.z; Bt[lk+3][li]=bv0.w;
    Bt[lk+4][li]=bv1.x; Bt[lk+5][li]=bv1.y; Bt[lk+6][li]=bv1.z; Bt[lk+7][li]=bv1.w;
    __syncthreads();
    #pragma unroll
    for (int k = 0; k < 32; ++k) {
      float4 a4 = *(const float4*)&At[k][tr*4];
      float4 b4 = *(const float4*)&Bt[k][tc*4];
      acc[0][0]+=a4.x*b4.x; acc[0][1]+=a4.x*b4.y; acc[0][2]+=a4.x*b4.z; acc[0][3]+=a4.x*b4.w;
      acc[1][0]+=a4.y*b4.x; acc[1][1]+=a4.y*b4.y; acc[1][2]+=a4.y*b4.z; acc[1][3]+=a4.y*b4.w;
      acc[2][0]+=a4.z*b4.x; acc[2][1]+=a4.z*b4.y; acc[2][2]+=a4.z*b4.z; acc[2][3]+=a4.z*b4.w;
      acc[3][0]+=a4.w*b4.x; acc[3][1]+=a4.w*b4.y; acc[3][2]+=a4.w*b4.z; acc[3][3]+=a4.w*b4.w;
    }
  }
  const int gc = g0 + tc * 4;
  float badd[4];
  #pragma unroll
  for (int jj = 0; jj < 4; ++jj) {
    int g = gc + jj;
    badd[jj] = (g < 1536) ? (bioux[g] + biouh[g]) : (bfx[g-1536] + bfh[g-1536]);
  }
  #pragma unroll
  for (int ii = 0; ii < 4; ++ii) {
    float4 r;
    r.x = acc[ii][0] + badd[0];
    r.y = acc[ii][1] + badd[1];
    r.z = acc[ii][2] + badd[2];
    r.w = acc[ii][3] + badd[3];
    size_t off = ((size_t)seq * SEQLEN + (size_t)(t0 + tr*4 + ii)) * 2048 + gc;
    *(float4*)(gx + off) = r;
  }
}

// ---------------- K2: persistent recurrent scan, 32 WGs, weights in registers -------------
// hbuf: [2 parity][512 k][4] = {h_l, tag, h_r, tag}, 16B atomic coherent stores.
// Thread (a=tid>>4, b=tid&15): owns gate-rows {i,o,u,f} for j = wg*16+a, cols [b*32,b*32+32).
// After the 16-lane reduce, lane b==0 holds all 4 gates of its j for BOTH seqs ->
// cell update + publish happen in-register, no second barrier, no pre[] LDS.
__global__ __launch_bounds__(256, 1) void lstm_scan(
    const float* __restrict__ Wiouh, const float* __restrict__ Wfh,
    const float* __restrict__ gx,
    float* __restrict__ hbuf,       // zeroed by memset (tags start at 0)
    float* __restrict__ hB)         // [2 seq][512]
{
  const int tid = threadIdx.x;
  const int wg = blockIdx.x;       // 0..31
  const int a = tid >> 4;          // 0..15  (j within WG)
  const int b = tid & 15;          // 0..15  (k-chunk)
  const bool owner = (b == 0);
  const int j = wg * 16 + a;       // global h index this thread's rows belong to

  // weights: rows {i,o,u,f} for j, cols b*32..b*32+31
  float w[4][32];
  #pragma unroll
  for (int r = 0; r < 4; ++r) {
    const float* row = (r < 3) ? (Wiouh + (size_t)(r * 512 + j) * MM)
                               : (Wfh + (size_t)j * MM);
    #pragma unroll
    for (int q = 0; q < 8; ++q) {
      float4 v = *(const float4*)(row + b * 32 + q * 4);
      w[r][q*4+0]=v.x; w[r][q*4+1]=v.y; w[r][q*4+2]=v.z; w[r][q*4+3]=v.w;
    }
  }

  // hsm: 16 chunks of 32 k-entries x {hl,hr}, padded 64->68 floats per chunk
  __shared__ __align__(16) float hsm[16 * 68];
  float cl = 0.0f, cr = 0.0f;      // persistent c state (valid in owner lanes)

  for (int t = 0; t < SEQLEN; ++t) {
    // ---- poll + load the 2 k-entries this thread stages (coherent, bypasses L1/L2) ----
    {
      const float* pp = hbuf + ((size_t)((t & 1) * 512 + tid * 2)) * 4;
      const float tf = (float)t;
      f32x4 r0, r1;
      for (;;) {
        asm volatile("global_load_dwordx4 %0, %2, off sc0 sc1\n\t"
                     "global_load_dwordx4 %1, %3, off sc0 sc1\n\t"
                     "s_waitcnt vmcnt(0)"
                     : "=&v"(r0), "=&v"(r1)
                     : "v"(pp), "v"(pp + 4)
                     : "memory");
        if (r0[1] >= tf && r1[1] >= tf) break;
        __builtin_amdgcn_s_sleep(1);
      }
      f32x4 hv; hv[0]=r0[0]; hv[1]=r0[2]; hv[2]=r1[0]; hv[3]=r1[2];
      *(f32x4*)&hsm[(tid >> 4) * 68 + (tid & 15) * 4] = hv;
    }
    __syncthreads();   // A: hsm complete

    // owner-only gx loads (plain cached; latency hides under LDS reads + FMA)
    float gl[4], gr[4];
    if (owner) {
      #pragma unroll
      for (int r = 0; r < 4; ++r) {
        gl[r] = gx[(size_t)t * 2048 + r * 512 + j];
        gr[r] = gx[((size_t)SEQLEN + t) * 2048 + r * 512 + j];
      }
    }

    // LDS -> registers (interleaved {hl,hr} pairs), 2-way-conflict-free
    float hl[32], hr[32];
    #pragma unroll
    for (int q = 0; q < 16; ++q) {
      f32x4 v = *(const f32x4*)&hsm[b * 68 + q * 4];
      hl[q*2+0] = v[0]; hr[q*2+0] = v[1];
      hl[q*2+1] = v[2]; hr[q*2+1] = v[3];
    }
    __syncthreads();   // B: hsm reads done; next iteration may overwrite

    // ---- GEMV partials: 4 gates x 2 seqs over 32 cols ----
    float al[4] = {0,0,0,0}, ar[4] = {0,0,0,0};
    #pragma unroll
    for (int k = 0; k < 32; ++k) {
      al[0] += w[0][k]*hl[k];
      al[1] += w[1][k]*hl[k];
      al[2] += w[2][k]*hl[k];
      al[3] += w[3][k]*hl[k];
      ar[0] += w[0][k]*hr[k];
      ar[1] += w[1][k]*hr[k];
      ar[2] += w[2][k]*hr[k];
      ar[3] += w[3][k]*hr[k];
    }
    #pragma unroll
    for (int m = 1; m < 16; m <<= 1) {
      #pragma unroll
      for (int r = 0; r < 4; ++r) {
        al[r] += __shfl_xor(al[r], m, 64);
        ar[r] += __shfl_xor(ar[r], m, 64);
      }
    }

    // ---- owner: cell update + coherent 16B publish {h_l, tag, h_r, tag} ----
    if (owner) {
      const float il = al[0]+gl[0], ol = al[1]+gl[1], ul = al[2]+gl[2], fl = al[3]+gl[3];
      const float ir = ar[0]+gr[0], orr = ar[1]+gr[1], ur = ar[2]+gr[2], fr = ar[3]+gr[3];
      cl = sigf(il) * tanhfast(ul) + sigf(fl) * cl;
      cr = sigf(ir) * tanhfast(ur) + sigf(fr) * cr;
      const float h2l = sigf(ol) * tanhfast(cl);
      const float h2r = sigf(orr) * tanhfast(cr);
      const float tg = (float)(t + 1);
      f32x4 st; st[0] = h2l; st[1] = tg; st[2] = h2r; st[3] = tg;
      float* dp = hbuf + ((size_t)(((t + 1) & 1) * 512 + j)) * 4;
      asm volatile("global_store_dwordx4 %0, %1, off sc0 sc1" :: "v"(dp), "v"(st) : "memory");
      if (t == SEQLEN - 1) {
        // hB = cell(x_last, 0, 0).h ; gate pre-acts are exactly gl/gr
        const float cBl = sigf(gl[0]) * tanhfast(gl[2]);
        const float cBr = sigf(gr[0]) * tanhfast(gr[2]);
        hB[j]       = sigf(gl[1]) * tanhfast(cBl);
        hB[512 + j] = sigf(gr[1]) * tanhfast(cBr);
      }
    }
  }
}

// ---------------- K3a: s = sigmoid(Wh @ vec + bh), 16 WGs x 16 rows ----------------
__global__ __launch_bounds__(256) void head1(
    const float* __restrict__ hbuf, const float* __restrict__ hB,
    const float* __restrict__ Wh, const float* __restrict__ bh,
    float* __restrict__ sv)
{
  __shared__ __align__(16) float vec[2048];
  const int tid = threadIdx.x;
  const int wg = blockIdx.x;  // 0..15
  // final h (tag 1024) lives at parity 0: entry k -> {h_l at k*4, h_r at k*4+2}
  for (int k = tid; k < 1024; k += 256) {
    float lv, rv;
    if (k < 512) { lv = hbuf[(size_t)k * 4]; rv = hbuf[(size_t)k * 4 + 2]; }
    else         { lv = hB[k - 512];         rv = hB[512 + (k - 512)]; }
    vec[k] = lv * rv;
    vec[1024 + k] = fabsf(lv - rv);
  }
  __syncthreads();
  const int row = wg * 16 + (tid >> 4);
  const int ln = tid & 15;
  const float* wr = Wh + (size_t)row * 2048 + ln * 128;
  const float* vp = vec + ln * 128;
  float acc = 0.0f;
  #pragma unroll
  for (int k = 0; k < 128; k += 4) {
    float4 wv = *(const float4*)(wr + k);
    float4 vv = *(const float4*)(vp + k);
    acc += wv.x*vv.x + wv.y*vv.y + wv.z*vv.z + wv.w*vv.w;
  }
  #pragma unroll
  for (int msk = 1; msk < 16; msk <<= 1) acc += __shfl_xor(acc, msk, 64);
  if (ln == 0) sv[row] = 1.0f / (1.0f + expf(-(acc + bh[row])));
}

// ---------------- K3b: logits = Wp @ s + bp ; log_softmax ----------------
__global__ __launch_bounds__(256) void head2(
    const float* __restrict__ sv, const float* __restrict__ Wp,
    const float* __restrict__ bp, float* __restrict__ out)
{
  __shared__ float s_l[256];
  __shared__ float lg[5];
  const int tid = threadIdx.x;
  s_l[tid] = sv[tid];
  __syncthreads();
  if (tid < 5) {
    float acc = bp[tid];
    for (int k = 0; k < 256; ++k) acc += Wp[tid*256 + k] * s_l[k];
    lg[tid] = acc;
  }
  __syncthreads();
  if (tid == 0) {
    float mx = lg[0];
    #pragma unroll
    for (int i = 1; i < 5; ++i) mx = fmaxf(mx, lg[i]);
    float sum = 0.0f;
    #pragma unroll
    for (int i = 0; i < 5; ++i) sum += expf(lg[i] - mx);
    const float lse = mx + logf(sum);
    #pragma unroll
    for (int i = 0; i < 5; ++i) out[i] = lg[i] - lse;
  }
}

extern "C" void kernel_launch(void* const* d_in, const int* in_sizes, int n_in,
                              void* d_out, int out_size, void* d_ws, size_t ws_size,
                              hipStream_t stream) {
  const int*   l_ids = (const int*)d_in[0];
  const int*   r_ids = (const int*)d_in[1];
  const float* emb   = (const float*)d_in[2];
  const float* Wioux = (const float*)d_in[3];
  const float* bioux = (const float*)d_in[4];
  const float* Wiouh = (const float*)d_in[5];
  const float* biouh = (const float*)d_in[6];
  const float* Wfx   = (const float*)d_in[7];
  const float* bfx   = (const float*)d_in[8];
  const float* Wfh   = (const float*)d_in[9];
  const float* bfh   = (const float*)d_in[10];
  const float* Wh    = (const float*)d_in[11];
  const float* bh    = (const float*)d_in[12];
  const float* Wp    = (const float*)d_in[13];
  const float* bp    = (const float*)d_in[14];
  float* out = (float*)d_out;

  // workspace layout (floats): Gx [2*1024*2048], hbuf [2*512*4], hB [1024], sv [256]
  float* gx   = (float*)d_ws;
  float* hbuf = gx + (size_t)2*1024*2048;
  float* hB   = hbuf + 4096;
  float* sv   = hB + 1024;

  // zero {h,tag} buffer + hB + sv each launch (graph-captured memset node)
  hipMemsetAsync(hbuf, 0, (4096 + 1024 + 256) * sizeof(float), stream);

  gx_gemm<<<dim3(1024), dim3(256), 0, stream>>>(l_ids, r_ids, emb, Wioux, Wfx,
                                                bioux, biouh, bfx, bfh, gx);
  lstm_scan<<<dim3(32), dim3(256), 0, stream>>>(Wiouh, Wfh, gx, hbuf, hB);
  head1<<<dim3(16), dim3(256), 0, stream>>>(hbuf, hB, Wh, bh, sv);
  head2<<<dim3(1), dim3(256), 0, stream>>>(sv, Wp, bp, out);
  (void)in_sizes; (void)n_in; (void)out_size; (void)ws_size;
}